// Round 12
// baseline (114.847 us; speedup 1.0000x reference)
//
#include <hip/hip_runtime.h>
#include <hip/hip_bf16.h>
#include <stdint.h>

#define SS 512
#define BB 32
#define TQ 128   // fallback tile
#define TG 64    // GEMM q-tile (R12: halved for occupancy/TLP)

typedef __bf16 bf16;
typedef __attribute__((ext_vector_type(8))) __bf16 bf16x8;
typedef __attribute__((ext_vector_type(4))) float f32x4;

// ---------------------------------------------------------------------------
// Kernel A (fallback path only): y = x everywhere.
// ---------------------------------------------------------------------------
__global__ __launch_bounds__(256) void copy_x_kernel(const float* __restrict__ x,
                                                     float* __restrict__ y) {
    size_t idx = (size_t)blockIdx.x * 256 + threadIdx.x;
    reinterpret_cast<float4*>(y)[idx] = reinterpret_cast<const float4*>(x)[idx];
}

// ---------------------------------------------------------------------------
// Gather: D2[rb][b][i] (uint4 = 8 bf16, e-th elem = D[b, i, r=rb*8+e])
//   D[b,i,r] = x[b, r, i-r] if r <= i else 0
// ---------------------------------------------------------------------------
__global__ __launch_bounds__(256) void gather_kernel(const float* __restrict__ x,
                                                     uint4* __restrict__ D2) {
    const int rb = blockIdx.x;   // 0..63
    const int b  = blockIdx.y;   // 0..31
    __shared__ float xs[8][516];

    const int t = threadIdx.x;
    const float* xb = x + ((size_t)b * SS + rb * 8) * SS;
#pragma unroll
    for (int k = 0; k < 4; ++k) {
        int task = t + 256 * k;
        int c4 = task & 127;
        int e  = task >> 7;
        float4 v = *reinterpret_cast<const float4*>(xb + (size_t)e * SS + c4 * 4);
        *reinterpret_cast<float4*>(&xs[e][c4 * 4]) = v;
    }
    __syncthreads();

    const int r0 = rb * 8;
#pragma unroll
    for (int k = 0; k < 2; ++k) {
        int i = t + 256 * k;
        bf16x8 pack;
#pragma unroll
        for (int e = 0; e < 8; ++e) {
            int c  = i - (r0 + e);
            int cc = c < 0 ? 0 : c;
            float v = xs[e][cc];
            pack[e] = (c >= 0) ? (bf16)v : (bf16)0.0f;
        }
        D2[((size_t)rb * BB + b) * SS + i] = __builtin_bit_cast(uint4, pack);
    }
}

// ---------------------------------------------------------------------------
// MFMA GEMM, q-tile=64 (R12): R7's depth-2 pipeline + raw barriers, but a
// narrower tile -> ~half the VGPR (one staging task, one wave-frag, acc x2),
// half the LDS (10.2 KB) -> more blocks/CU -> more independent W streams
// per CU to fill the HBM pipe. W traffic unchanged (each element read once).
//   step k: MFMA(k) from LDS buf[k&1]; issue W/A(k+2); cvt+ds_write W(k+1);
//   lgkmcnt(0) + raw s_barrier (global loads stay in flight).
// O output bf16, coalesced [b][i][q]; shear kernel finishes.
// i-mapping XCD-balanced (runs of 8, heavy-first).
// ---------------------------------------------------------------------------
__global__ __launch_bounds__(256) void mfma_gemm_pipe(const uint4* __restrict__ D2,
                                                      const float* __restrict__ W,
                                                      const float* __restrict__ bias,
                                                      bf16* __restrict__ O) {
    const int bid = (int)blockIdx.x;                 // 0..511
    const int xcd = bid & 7;
    const int m   = bid >> 3;                        // 0..63
    const int run = xcd + 8 * (m >> 3);
    const int i   = (SS - 1) - (run * 8 + (m & 7));  // heavy-first per XCD
    const int q0  = (int)blockIdx.y * TG;
    if (q0 > i) return;

    const int qmax = ((i >> 4) + 1) * 16;
    const int qhi  = min(qmax - q0, TG);
    const int nk   = (i >> 5) + 1;

    __shared__ bf16 Bs[2][TG][40];                   // 10.2 KB

    const int t    = (int)threadIdx.x;
    const int lane = t & 63;
    const int w    = t >> 6;
    const int l15  = lane & 15;
    const int lg   = lane >> 4;

    f32x4 acc00 = (f32x4)0.0f, acc01 = (f32x4)0.0f;

    const float* Wi  = W + (size_t)i * SS * SS;
    const uint4* D2i = D2 + i;

    const int qq0 = t >> 2, ch0 = t & 3;             // one task/thread (64 rows x 4 chunks)
    const bool st0 = (t < qhi * 4);

    const int qf0 = q0 + w * 16;                     // wave w owns rows [16w,16w+16)
    const bool v0 = (qf0 <= i);                      // wave-uniform

    f32x4 eW0, eW1, oW0, oW1;                        // named reg sets (rule #20)
    uint4 eA0, eA1, oA0, oA1;

#define ISSUE_W(kk, d0, d1)                                                    \
    do {                                                                       \
        if (st0) {                                                             \
            const float* wp_ = Wi + (size_t)(q0 + qq0) * SS + (kk) * 32 + ch0 * 8; \
            d0 = *reinterpret_cast<const f32x4*>(wp_);                         \
            d1 = *reinterpret_cast<const f32x4*>(wp_ + 4);                     \
        }                                                                      \
    } while (0)

#define ISSUE_A(kk, a0_, a1_)                                                  \
    do {                                                                       \
        const int rb_ = ((kk) * 32) >> 3;                                      \
        a0_ = D2i[(size_t)((rb_ + lg) * BB + l15) * SS];                       \
        a1_ = D2i[(size_t)((rb_ + lg) * BB + 16 + l15) * SS];                  \
    } while (0)

#define WRITE_B(buf_, d0, d1)                                                  \
    do {                                                                       \
        if (st0) {                                                             \
            bf16x8 pk_;                                                        \
            pk_[0]=(bf16)d0.x; pk_[1]=(bf16)d0.y; pk_[2]=(bf16)d0.z; pk_[3]=(bf16)d0.w; \
            pk_[4]=(bf16)d1.x; pk_[5]=(bf16)d1.y; pk_[6]=(bf16)d1.z; pk_[7]=(bf16)d1.w; \
            *reinterpret_cast<uint4*>(&Bs[buf_][qq0][ch0 * 8]) = __builtin_bit_cast(uint4, pk_); \
        }                                                                      \
    } while (0)

// raw barrier: drain LDS only; global loads stay in flight (counted vmcnt).
#define BARRIER()                                                              \
    do {                                                                       \
        asm volatile("s_waitcnt lgkmcnt(0)" ::: "memory");                     \
        __builtin_amdgcn_s_barrier();                                          \
        __builtin_amdgcn_sched_barrier(0);                                     \
    } while (0)

#define MFMA_STEP(buf_, aa0_, aa1_)                                            \
    do {                                                                       \
        const bf16x8 a0v_ = __builtin_bit_cast(bf16x8, aa0_);                  \
        const bf16x8 a1v_ = __builtin_bit_cast(bf16x8, aa1_);                  \
        if (v0) {                                                              \
            uint4 bv_ = *reinterpret_cast<const uint4*>(&Bs[buf_][w * 16 + l15][lg * 8]); \
            bf16x8 bb_ = __builtin_bit_cast(bf16x8, bv_);                      \
            acc00 = __builtin_amdgcn_mfma_f32_16x16x32_bf16(a0v_, bb_, acc00, 0, 0, 0); \
            acc01 = __builtin_amdgcn_mfma_f32_16x16x32_bf16(a1v_, bb_, acc01, 0, 0, 0); \
        }                                                                      \
    } while (0)

    // prologue: W(0),A(0) -> even set; W(1),A(1) -> odd set; stage buf0.
    ISSUE_W(0, eW0, eW1);
    ISSUE_A(0, eA0, eA1);
    if (nk > 1) { ISSUE_W(1, oW0, oW1); ISSUE_A(1, oA0, oA1); }
    WRITE_B(0, eW0, eW1);
    BARRIER();

    for (int kk = 0; kk < nk; kk += 2) {
        // ---- even step kk: B from buf0, A = even set ----
        MFMA_STEP(0, eA0, eA1);
        if (kk + 2 < nk) {
            ISSUE_W(kk + 2, eW0, eW1);
            ISSUE_A(kk + 2, eA0, eA1);
        }
        if (kk + 1 < nk) {
            WRITE_B(1, oW0, oW1);                // W(k+1): issued 1 step ago
            BARRIER();
            // ---- odd step kk+1: B from buf1, A = odd set ----
            MFMA_STEP(1, oA0, oA1);
            if (kk + 3 < nk) {
                ISSUE_W(kk + 3, oW0, oW1);
                ISSUE_A(kk + 3, oA0, oA1);
            }
            if (kk + 2 < nk) {
                WRITE_B(0, eW0, eW1);
                BARRIER();
            }
        }
    }

#undef ISSUE_W
#undef ISSUE_A
#undef WRITE_B
#undef BARRIER
#undef MFMA_STEP

    // epilogue: C/D layout col(q)=lane&15, row(b)=(lane>>4)*4+reg; O is bf16.
    if (v0) {
        const int q = qf0 + l15;
        const float bv = bias[(size_t)i * SS + q];
#pragma unroll
        for (int v = 0; v < 4; ++v) {
            O[((size_t)(lg * 4 + v) * SS + i) * SS + q]      = (bf16)(acc00[v] + bv);
            O[((size_t)(16 + lg * 4 + v) * SS + i) * SS + q] = (bf16)(acc01[v] + bv);
        }
    }
}

// ---------------------------------------------------------------------------
// Shear: y[b][q][c] = (q+c < S) ? O[b][q+c][q] : x[b][q][c].  O is bf16.
// ---------------------------------------------------------------------------
__global__ __launch_bounds__(256) void shear_kernel(const bf16* __restrict__ O,
                                                    const float* __restrict__ x,
                                                    float* __restrict__ y) {
    const int c0 = (int)blockIdx.x * 64;
    const int q0 = (int)blockIdx.y * 64;
    const int b  = (int)blockIdx.z;
    const int t  = (int)threadIdx.x;
    const float* xb = x + (size_t)b * SS * SS;
    float* yb       = y + (size_t)b * SS * SS;
    const int i0 = q0 + c0;

    if (i0 >= SS) {   // pure passthrough tile
#pragma unroll
        for (int k = 0; k < 4; ++k) {
            int task = t + 256 * k;
            int qq = task >> 4, c4 = (task & 15) * 4;
            size_t off = (size_t)(q0 + qq) * SS + c0 + c4;
            *reinterpret_cast<float4*>(yb + off) =
                *reinterpret_cast<const float4*>(xb + off);
        }
        return;
    }

    __shared__ float Os[127 * 67];
    const int nrows = min(127, SS - i0);
    const bf16* Ob = O + (size_t)b * SS * SS;

    for (int task = t; task < nrows * 8; task += 256) {
        int rr = task >> 3, c8 = (task & 7) * 8;
        bf16x8 v = *reinterpret_cast<const bf16x8*>(Ob + (size_t)(i0 + rr) * SS + q0 + c8);
        float* d = &Os[rr * 67 + c8];
#pragma unroll
        for (int e = 0; e < 8; ++e) d[e] = (float)v[e];
    }
    __syncthreads();

#pragma unroll
    for (int k = 0; k < 4; ++k) {
        int task = t + 256 * k;
        int qq = task >> 4, c4 = (task & 15) * 4;
        int q = q0 + qq, c = c0 + c4;
        float4 o;
        if (i0 + qq + c4 + 3 < SS) {
            o.x = Os[(qq + c4 + 0) * 67 + qq];
            o.y = Os[(qq + c4 + 1) * 67 + qq];
            o.z = Os[(qq + c4 + 2) * 67 + qq];
            o.w = Os[(qq + c4 + 3) * 67 + qq];
        } else {
            float tmp[4];
#pragma unroll
            for (int kk = 0; kk < 4; ++kk) {
                tmp[kk] = (q + c + kk < SS) ? Os[(qq + c4 + kk) * 67 + qq]
                                            : xb[(size_t)q * SS + c + kk];
            }
            o = make_float4(tmp[0], tmp[1], tmp[2], tmp[3]);
        }
        *reinterpret_cast<float4*>(yb + (size_t)q * SS + c) = o;
    }
}

// ---------------------------------------------------------------------------
// f32 fallback (round-1), only if ws_size is tiny.
// ---------------------------------------------------------------------------
#define FTK 32
#define FWROW (TQ + 4)
__global__ __launch_bounds__(256) void diag_gemm_fallback(const float* __restrict__ x,
                                                          const float* __restrict__ W,
                                                          const float* __restrict__ bias,
                                                          float* __restrict__ y) {
    const int i  = (SS - 1) - (int)blockIdx.y;
    const int q0 = (int)blockIdx.x * TQ;
    if (q0 > i) return;
    __shared__ float Ds[FTK][BB];
    __shared__ float Ws[FTK][FWROW];
    const int tid = (int)threadIdx.x;
    const int qg  = tid & 31;
    const int bg  = tid >> 5;
    float acc[4][4];
#pragma unroll
    for (int a = 0; a < 4; ++a)
#pragma unroll
        for (int c = 0; c < 4; ++c) acc[a][c] = 0.0f;
    const float* Wi = W + (size_t)i * SS * SS;
    for (int r0 = 0; r0 <= i; r0 += FTK) {
        __syncthreads();
        {
            const int rr = tid >> 3;
            const int b4 = (tid & 7) * 4;
            const int r  = r0 + rr;
            float4 dv = make_float4(0.f, 0.f, 0.f, 0.f);
            if (r <= i) {
                const int col = i - r;
                dv.x = x[((size_t)(b4 + 0) * SS + r) * SS + col];
                dv.y = x[((size_t)(b4 + 1) * SS + r) * SS + col];
                dv.z = x[((size_t)(b4 + 2) * SS + r) * SS + col];
                dv.w = x[((size_t)(b4 + 3) * SS + r) * SS + col];
            }
            *reinterpret_cast<float4*>(&Ds[rr][b4]) = dv;
        }
#pragma unroll
        for (int l = 0; l < 4; ++l) {
            const int idx = tid + 256 * l;
            const int qL  = idx >> 3;
            const int rc  = idx & 7;
            const int r   = r0 + rc * 4;
            const float* wp = Wi + (size_t)(q0 + qL) * SS;
            float4 wv;
            if (r + 3 < SS) {
                wv = *reinterpret_cast<const float4*>(wp + r);
            } else {
                wv.x = wp[min(r + 0, SS - 1)];
                wv.y = wp[min(r + 1, SS - 1)];
                wv.z = wp[min(r + 2, SS - 1)];
                wv.w = wp[min(r + 3, SS - 1)];
            }
            Ws[rc * 4 + 0][qL] = wv.x;
            Ws[rc * 4 + 1][qL] = wv.y;
            Ws[rc * 4 + 2][qL] = wv.z;
            Ws[rc * 4 + 3][qL] = wv.w;
        }
        __syncthreads();
#pragma unroll
        for (int rr = 0; rr < FTK; ++rr) {
            const float4 d4 = *reinterpret_cast<const float4*>(&Ds[rr][bg * 4]);
            const float4 w4 = *reinterpret_cast<const float4*>(&Ws[rr][qg * 4]);
            acc[0][0] = fmaf(d4.x, w4.x, acc[0][0]); acc[0][1] = fmaf(d4.x, w4.y, acc[0][1]);
            acc[0][2] = fmaf(d4.x, w4.z, acc[0][2]); acc[0][3] = fmaf(d4.x, w4.w, acc[0][3]);
            acc[1][0] = fmaf(d4.y, w4.x, acc[1][0]); acc[1][1] = fmaf(d4.y, w4.y, acc[1][1]);
            acc[1][2] = fmaf(d4.y, w4.z, acc[1][2]); acc[1][3] = fmaf(d4.y, w4.w, acc[1][3]);
            acc[2][0] = fmaf(d4.z, w4.x, acc[2][0]); acc[2][1] = fmaf(d4.z, w4.y, acc[2][1]);
            acc[2][2] = fmaf(d4.z, w4.z, acc[2][2]); acc[2][3] = fmaf(d4.z, w4.w, acc[2][3]);
            acc[3][0] = fmaf(d4.w, w4.x, acc[3][0]); acc[3][1] = fmaf(d4.w, w4.y, acc[3][1]);
            acc[3][2] = fmaf(d4.w, w4.z, acc[3][2]); acc[3][3] = fmaf(d4.w, w4.w, acc[3][3]);
        }
    }
    const int qb = q0 + qg * 4;
    const float4 bv = *reinterpret_cast<const float4*>(bias + (size_t)i * SS + qb);
    const float bvals[4] = {bv.x, bv.y, bv.z, bv.w};
#pragma unroll
    for (int bi = 0; bi < 4; ++bi) {
        const int b = bg * 4 + bi;
        float* yb = y + (size_t)b * SS * SS;
#pragma unroll
        for (int qi = 0; qi < 4; ++qi) {
            const int q = qb + qi;
            if (q <= i) yb[(size_t)q * SS + (i - q)] = acc[bi][qi] + bvals[qi];
        }
    }
}

extern "C" void kernel_launch(void* const* d_in, const int* in_sizes, int n_in,
                              void* d_out, int out_size, void* d_ws, size_t ws_size,
                              hipStream_t stream) {
    const float* x    = (const float*)d_in[0];
    const float* W    = (const float*)d_in[1];
    const float* bias = (const float*)d_in[2];
    float* y          = (float*)d_out;

    const size_t D2_bytes = (size_t)64 * BB * SS * 16;           // 16.8 MB
    const size_t O_bytes  = (size_t)BB * SS * SS * sizeof(bf16); // 16.8 MB

    if (ws_size >= D2_bytes + O_bytes) {
        uint4* D2 = (uint4*)d_ws;
        bf16*  O  = (bf16*)((char*)d_ws + D2_bytes);
        gather_kernel<<<dim3(64, 32), dim3(256), 0, stream>>>(x, D2);
        mfma_gemm_pipe<<<dim3(512, 8), dim3(256), 0, stream>>>(D2, W, bias, O);
        shear_kernel<<<dim3(8, 8, 32), dim3(256), 0, stream>>>(O, x, y);
    } else {
        copy_x_kernel<<<dim3(8192), dim3(256), 0, stream>>>(x, y);
        diag_gemm_fallback<<<dim3(SS / TQ, SS), dim3(256), 0, stream>>>(x, W, bias, y);
    }
}

// Round 13
// 95.075 us; speedup vs baseline: 1.2080x; 1.2080x over previous
//
#include <hip/hip_runtime.h>
#include <hip/hip_bf16.h>
#include <stdint.h>

#define SS 512
#define BB 32
#define TQ 128

typedef __bf16 bf16;
typedef __attribute__((ext_vector_type(8))) __bf16 bf16x8;
typedef __attribute__((ext_vector_type(4))) float f32x4;

// ---------------------------------------------------------------------------
// Kernel A (fallback path only): y = x everywhere.
// ---------------------------------------------------------------------------
__global__ __launch_bounds__(256) void copy_x_kernel(const float* __restrict__ x,
                                                     float* __restrict__ y) {
    size_t idx = (size_t)blockIdx.x * 256 + threadIdx.x;
    reinterpret_cast<float4*>(y)[idx] = reinterpret_cast<const float4*>(x)[idx];
}

// ---------------------------------------------------------------------------
// Gather: D2[rb][b][i] (uint4 = 8 bf16, e-th elem = D[b, i, r=rb*8+e])
//   D[b,i,r] = x[b, r, i-r] if r <= i else 0
// PLUS: writes y's pure-passthrough region (q+c >= S, y=x) straight from the
// staged LDS rows, so the shear kernel can skip its 28/64 passthrough tiles.
// ---------------------------------------------------------------------------
__global__ __launch_bounds__(256) void gather_kernel(const float* __restrict__ x,
                                                     uint4* __restrict__ D2,
                                                     float* __restrict__ y) {
    const int rb = blockIdx.x;   // 0..63
    const int b  = blockIdx.y;   // 0..31
    __shared__ float xs[8][516];

    const int t = threadIdx.x;
    const float* xb = x + ((size_t)b * SS + rb * 8) * SS;
#pragma unroll
    for (int k = 0; k < 4; ++k) {
        int task = t + 256 * k;
        int c4 = task & 127;
        int e  = task >> 7;
        float4 v = *reinterpret_cast<const float4*>(xb + (size_t)e * SS + c4 * 4);
        *reinterpret_cast<float4*>(&xs[e][c4 * 4]) = v;
    }
    __syncthreads();

    const int r0 = rb * 8;
#pragma unroll
    for (int k = 0; k < 2; ++k) {
        int i = t + 256 * k;
        bf16x8 pack;
#pragma unroll
        for (int e = 0; e < 8; ++e) {
            int c  = i - (r0 + e);
            int cc = c < 0 ? 0 : c;
            float v = xs[e][cc];
            pack[e] = (c >= 0) ? (bf16)v : (bf16)0.0f;
        }
        D2[((size_t)rb * BB + b) * SS + i] = __builtin_bit_cast(uint4, pack);
    }

    // passthrough: y[b][q][c] = x[b][q][c] for q + c >= SS  (rows q = r0+e)
    float* yb = y + (size_t)b * SS * SS;
#pragma unroll
    for (int k = 0; k < 4; ++k) {
        int task = t + 256 * k;          // 1024 tasks = 8 rows x 128 chunks
        int e  = task >> 7;
        int c4 = (task & 127) * 4;
        int q  = r0 + e;
        int lo = SS - q;                 // first passthrough column
        if (c4 + 4 > lo) {
            if (c4 >= lo) {              // whole chunk is passthrough
                *reinterpret_cast<float4*>(yb + (size_t)q * SS + c4) =
                    *reinterpret_cast<const float4*>(&xs[e][c4]);
            } else {                     // straddling chunk: element-wise tail
                for (int kk = lo - c4; kk < 4; ++kk)
                    yb[(size_t)q * SS + c4 + kk] = xs[e][c4 + kk];
            }
        }
    }
}

// ---------------------------------------------------------------------------
// MFMA GEMM (R7, best measured): depth-2 pipelined, raw barriers (lgkmcnt
// only -- global loads stay in flight across the barrier via counted vmcnt).
//   step k: MFMA(k) from LDS buf[k&1]; issue W/A(k+2); cvt+ds_write W(k+1).
// O output bf16, coalesced [b][i][q]; shear kernel finishes.
// i-mapping XCD-balanced (runs of 8, heavy-first).
// ---------------------------------------------------------------------------
__global__ __launch_bounds__(256) void mfma_gemm_pipe(const uint4* __restrict__ D2,
                                                      const float* __restrict__ W,
                                                      const float* __restrict__ bias,
                                                      bf16* __restrict__ O) {
    const int bid = (int)blockIdx.x;                 // 0..511
    const int xcd = bid & 7;
    const int m   = bid >> 3;                        // 0..63
    const int run = xcd + 8 * (m >> 3);
    const int i   = (SS - 1) - (run * 8 + (m & 7));  // heavy-first per XCD
    const int q0  = (int)blockIdx.y * TQ;
    if (q0 > i) return;

    const int qmax = ((i >> 4) + 1) * 16;
    const int qhi  = min(qmax - q0, TQ);
    const int nk   = (i >> 5) + 1;

    __shared__ bf16 Bs[2][TQ][40];                   // pitch 40: ~2-way max alias

    const int t    = (int)threadIdx.x;
    const int lane = t & 63;
    const int w    = t >> 6;
    const int l15  = lane & 15;
    const int lg   = lane >> 4;

    f32x4 acc00 = (f32x4)0.0f, acc01 = (f32x4)0.0f;
    f32x4 acc10 = (f32x4)0.0f, acc11 = (f32x4)0.0f;

    const float* Wi  = W + (size_t)i * SS * SS;
    const uint4* D2i = D2 + i;

    const int qq0 = t >> 2,         ch0 = t & 3;
    const int qq1 = (t + 256) >> 2, ch1 = (t + 256) & 3;
    const bool st0 = (t < qhi * 4);
    const bool st1 = (t + 256 < qhi * 4);

    const int qf0 = q0 + w * 16;
    const int qf1 = q0 + 64 + w * 16;
    const bool v0 = (qf0 <= i);                      // wave-uniform
    const bool v1 = (qf1 <= i);

    f32x4 eW0, eW1, eW2, eW3;                        // even-slot W staging regs
    f32x4 oW0, oW1, oW2, oW3;                        // odd-slot
    uint4 eA0, eA1, oA0, oA1;                        // A frags even/odd

#define ISSUE_W(kk, d0, d1, d2, d3)                                            \
    do {                                                                       \
        const int r0_ = (kk) * 32;                                             \
        if (st0) {                                                             \
            const float* wp_ = Wi + (size_t)(q0 + qq0) * SS + r0_ + ch0 * 8;   \
            d0 = *reinterpret_cast<const f32x4*>(wp_);                         \
            d1 = *reinterpret_cast<const f32x4*>(wp_ + 4);                     \
        }                                                                      \
        if (st1) {                                                             \
            const float* wp_ = Wi + (size_t)(q0 + qq1) * SS + r0_ + ch1 * 8;   \
            d2 = *reinterpret_cast<const f32x4*>(wp_);                         \
            d3 = *reinterpret_cast<const f32x4*>(wp_ + 4);                     \
        }                                                                      \
    } while (0)

#define ISSUE_A(kk, a0_, a1_)                                                  \
    do {                                                                       \
        const int rb_ = ((kk) * 32) >> 3;                                      \
        a0_ = D2i[(size_t)((rb_ + lg) * BB + l15) * SS];                       \
        a1_ = D2i[(size_t)((rb_ + lg) * BB + 16 + l15) * SS];                  \
    } while (0)

#define WRITE_B(buf_, d0, d1, d2, d3)                                          \
    do {                                                                       \
        if (st0) {                                                             \
            bf16x8 pk_;                                                        \
            pk_[0]=(bf16)d0.x; pk_[1]=(bf16)d0.y; pk_[2]=(bf16)d0.z; pk_[3]=(bf16)d0.w; \
            pk_[4]=(bf16)d1.x; pk_[5]=(bf16)d1.y; pk_[6]=(bf16)d1.z; pk_[7]=(bf16)d1.w; \
            *reinterpret_cast<uint4*>(&Bs[buf_][qq0][ch0 * 8]) = __builtin_bit_cast(uint4, pk_); \
        }                                                                      \
        if (st1) {                                                             \
            bf16x8 pk_;                                                        \
            pk_[0]=(bf16)d2.x; pk_[1]=(bf16)d2.y; pk_[2]=(bf16)d2.z; pk_[3]=(bf16)d2.w; \
            pk_[4]=(bf16)d3.x; pk_[5]=(bf16)d3.y; pk_[6]=(bf16)d3.z; pk_[7]=(bf16)d3.w; \
            *reinterpret_cast<uint4*>(&Bs[buf_][qq1][ch1 * 8]) = __builtin_bit_cast(uint4, pk_); \
        }                                                                      \
    } while (0)

// raw barrier: drain LDS only; global loads stay in flight (counted vmcnt).
#define BARRIER()                                                              \
    do {                                                                       \
        asm volatile("s_waitcnt lgkmcnt(0)" ::: "memory");                     \
        __builtin_amdgcn_s_barrier();                                          \
        __builtin_amdgcn_sched_barrier(0);                                     \
    } while (0)

#define MFMA_STEP(buf_, aa0_, aa1_)                                            \
    do {                                                                       \
        const bf16x8 a0v_ = __builtin_bit_cast(bf16x8, aa0_);                  \
        const bf16x8 a1v_ = __builtin_bit_cast(bf16x8, aa1_);                  \
        if (v0) {                                                              \
            uint4 bv_ = *reinterpret_cast<const uint4*>(&Bs[buf_][w * 16 + l15][lg * 8]); \
            bf16x8 bb_ = __builtin_bit_cast(bf16x8, bv_);                      \
            acc00 = __builtin_amdgcn_mfma_f32_16x16x32_bf16(a0v_, bb_, acc00, 0, 0, 0); \
            acc01 = __builtin_amdgcn_mfma_f32_16x16x32_bf16(a1v_, bb_, acc01, 0, 0, 0); \
        }                                                                      \
        if (v1) {                                                              \
            uint4 bv_ = *reinterpret_cast<const uint4*>(&Bs[buf_][64 + w * 16 + l15][lg * 8]); \
            bf16x8 bb_ = __builtin_bit_cast(bf16x8, bv_);                      \
            acc10 = __builtin_amdgcn_mfma_f32_16x16x32_bf16(a0v_, bb_, acc10, 0, 0, 0); \
            acc11 = __builtin_amdgcn_mfma_f32_16x16x32_bf16(a1v_, bb_, acc11, 0, 0, 0); \
        }                                                                      \
    } while (0)

    // prologue: W(0),A(0) -> even set; W(1),A(1) -> odd set; stage buf0.
    ISSUE_W(0, eW0, eW1, eW2, eW3);
    ISSUE_A(0, eA0, eA1);
    if (nk > 1) { ISSUE_W(1, oW0, oW1, oW2, oW3); ISSUE_A(1, oA0, oA1); }
    WRITE_B(0, eW0, eW1, eW2, eW3);
    BARRIER();

    for (int kk = 0; kk < nk; kk += 2) {
        // ---- even step kk: B from buf0, A = even set ----
        MFMA_STEP(0, eA0, eA1);
        if (kk + 2 < nk) {
            ISSUE_W(kk + 2, eW0, eW1, eW2, eW3);
            ISSUE_A(kk + 2, eA0, eA1);
        }
        if (kk + 1 < nk) {
            WRITE_B(1, oW0, oW1, oW2, oW3);      // W(k+1): issued 1 step ago
            BARRIER();
            // ---- odd step kk+1: B from buf1, A = odd set ----
            MFMA_STEP(1, oA0, oA1);
            if (kk + 3 < nk) {
                ISSUE_W(kk + 3, oW0, oW1, oW2, oW3);
                ISSUE_A(kk + 3, oA0, oA1);
            }
            if (kk + 2 < nk) {
                WRITE_B(0, eW0, eW1, eW2, eW3);
                BARRIER();
            }
        }
    }

#undef ISSUE_W
#undef ISSUE_A
#undef WRITE_B
#undef BARRIER
#undef MFMA_STEP

    // epilogue: C/D layout col(q)=lane&15, row(b)=(lane>>4)*4+reg; O is bf16.
    if (v0) {
        const int q = qf0 + l15;
        const float bv = bias[(size_t)i * SS + q];
#pragma unroll
        for (int v = 0; v < 4; ++v) {
            O[((size_t)(lg * 4 + v) * SS + i) * SS + q]      = (bf16)(acc00[v] + bv);
            O[((size_t)(16 + lg * 4 + v) * SS + i) * SS + q] = (bf16)(acc01[v] + bv);
        }
    }
    if (v1) {
        const int q = qf1 + l15;
        const float bv = bias[(size_t)i * SS + q];
#pragma unroll
        for (int v = 0; v < 4; ++v) {
            O[((size_t)(lg * 4 + v) * SS + i) * SS + q]      = (bf16)(acc10[v] + bv);
            O[((size_t)(16 + lg * 4 + v) * SS + i) * SS + q] = (bf16)(acc11[v] + bv);
        }
    }
}

// ---------------------------------------------------------------------------
// Shear: y[b][q][c] = (q+c < S) ? O[b][q+c][q] : x[b][q][c].  O is bf16.
// Pure passthrough tiles (i0 >= S) are handled by the gather kernel now.
// ---------------------------------------------------------------------------
__global__ __launch_bounds__(256) void shear_kernel(const bf16* __restrict__ O,
                                                    const float* __restrict__ x,
                                                    float* __restrict__ y) {
    const int c0 = (int)blockIdx.x * 64;
    const int q0 = (int)blockIdx.y * 64;
    const int b  = (int)blockIdx.z;
    const int t  = (int)threadIdx.x;
    const float* xb = x + (size_t)b * SS * SS;
    float* yb       = y + (size_t)b * SS * SS;
    const int i0 = q0 + c0;

    if (i0 >= SS) return;   // passthrough tile: gather kernel wrote it

    __shared__ float Os[127 * 67];
    const int nrows = min(127, SS - i0);
    const bf16* Ob = O + (size_t)b * SS * SS;

    for (int task = t; task < nrows * 8; task += 256) {
        int rr = task >> 3, c8 = (task & 7) * 8;
        bf16x8 v = *reinterpret_cast<const bf16x8*>(Ob + (size_t)(i0 + rr) * SS + q0 + c8);
        float* d = &Os[rr * 67 + c8];
#pragma unroll
        for (int e = 0; e < 8; ++e) d[e] = (float)v[e];
    }
    __syncthreads();

#pragma unroll
    for (int k = 0; k < 4; ++k) {
        int task = t + 256 * k;
        int qq = task >> 4, c4 = (task & 15) * 4;
        int q = q0 + qq, c = c0 + c4;
        float4 o;
        if (i0 + qq + c4 + 3 < SS) {
            o.x = Os[(qq + c4 + 0) * 67 + qq];
            o.y = Os[(qq + c4 + 1) * 67 + qq];
            o.z = Os[(qq + c4 + 2) * 67 + qq];
            o.w = Os[(qq + c4 + 3) * 67 + qq];
        } else {
            float tmp[4];
#pragma unroll
            for (int kk = 0; kk < 4; ++kk) {
                tmp[kk] = (q + c + kk < SS) ? Os[(qq + c4 + kk) * 67 + qq]
                                            : xb[(size_t)q * SS + c + kk];
            }
            o = make_float4(tmp[0], tmp[1], tmp[2], tmp[3]);
        }
        *reinterpret_cast<float4*>(yb + (size_t)q * SS + c) = o;
    }
}

// ---------------------------------------------------------------------------
// f32 fallback (round-1), only if ws_size is tiny.
// ---------------------------------------------------------------------------
#define FTK 32
#define FWROW (TQ + 4)
__global__ __launch_bounds__(256) void diag_gemm_fallback(const float* __restrict__ x,
                                                          const float* __restrict__ W,
                                                          const float* __restrict__ bias,
                                                          float* __restrict__ y) {
    const int i  = (SS - 1) - (int)blockIdx.y;
    const int q0 = (int)blockIdx.x * TQ;
    if (q0 > i) return;
    __shared__ float Ds[FTK][BB];
    __shared__ float Ws[FTK][FWROW];
    const int tid = (int)threadIdx.x;
    const int qg  = tid & 31;
    const int bg  = tid >> 5;
    float acc[4][4];
#pragma unroll
    for (int a = 0; a < 4; ++a)
#pragma unroll
        for (int c = 0; c < 4; ++c) acc[a][c] = 0.0f;
    const float* Wi = W + (size_t)i * SS * SS;
    for (int r0 = 0; r0 <= i; r0 += FTK) {
        __syncthreads();
        {
            const int rr = tid >> 3;
            const int b4 = (tid & 7) * 4;
            const int r  = r0 + rr;
            float4 dv = make_float4(0.f, 0.f, 0.f, 0.f);
            if (r <= i) {
                const int col = i - r;
                dv.x = x[((size_t)(b4 + 0) * SS + r) * SS + col];
                dv.y = x[((size_t)(b4 + 1) * SS + r) * SS + col];
                dv.z = x[((size_t)(b4 + 2) * SS + r) * SS + col];
                dv.w = x[((size_t)(b4 + 3) * SS + r) * SS + col];
            }
            *reinterpret_cast<float4*>(&Ds[rr][b4]) = dv;
        }
#pragma unroll
        for (int l = 0; l < 4; ++l) {
            const int idx = tid + 256 * l;
            const int qL  = idx >> 3;
            const int rc  = idx & 7;
            const int r   = r0 + rc * 4;
            const float* wp = Wi + (size_t)(q0 + qL) * SS;
            float4 wv;
            if (r + 3 < SS) {
                wv = *reinterpret_cast<const float4*>(wp + r);
            } else {
                wv.x = wp[min(r + 0, SS - 1)];
                wv.y = wp[min(r + 1, SS - 1)];
                wv.z = wp[min(r + 2, SS - 1)];
                wv.w = wp[min(r + 3, SS - 1)];
            }
            Ws[rc * 4 + 0][qL] = wv.x;
            Ws[rc * 4 + 1][qL] = wv.y;
            Ws[rc * 4 + 2][qL] = wv.z;
            Ws[rc * 4 + 3][qL] = wv.w;
        }
        __syncthreads();
#pragma unroll
        for (int rr = 0; rr < FTK; ++rr) {
            const float4 d4 = *reinterpret_cast<const float4*>(&Ds[rr][bg * 4]);
            const float4 w4 = *reinterpret_cast<const float4*>(&Ws[rr][qg * 4]);
            acc[0][0] = fmaf(d4.x, w4.x, acc[0][0]); acc[0][1] = fmaf(d4.x, w4.y, acc[0][1]);
            acc[0][2] = fmaf(d4.x, w4.z, acc[0][2]); acc[0][3] = fmaf(d4.x, w4.w, acc[0][3]);
            acc[1][0] = fmaf(d4.y, w4.x, acc[1][0]); acc[1][1] = fmaf(d4.y, w4.y, acc[1][1]);
            acc[1][2] = fmaf(d4.y, w4.z, acc[1][2]); acc[1][3] = fmaf(d4.y, w4.w, acc[1][3]);
            acc[2][0] = fmaf(d4.z, w4.x, acc[2][0]); acc[2][1] = fmaf(d4.z, w4.y, acc[2][1]);
            acc[2][2] = fmaf(d4.z, w4.z, acc[2][2]); acc[2][3] = fmaf(d4.z, w4.w, acc[2][3]);
            acc[3][0] = fmaf(d4.w, w4.x, acc[3][0]); acc[3][1] = fmaf(d4.w, w4.y, acc[3][1]);
            acc[3][2] = fmaf(d4.w, w4.z, acc[3][2]); acc[3][3] = fmaf(d4.w, w4.w, acc[3][3]);
        }
    }
    const int qb = q0 + qg * 4;
    const float4 bv = *reinterpret_cast<const float4*>(bias + (size_t)i * SS + qb);
    const float bvals[4] = {bv.x, bv.y, bv.z, bv.w};
#pragma unroll
    for (int bi = 0; bi < 4; ++bi) {
        const int b = bg * 4 + bi;
        float* yb = y + (size_t)b * SS * SS;
#pragma unroll
        for (int qi = 0; qi < 4; ++qi) {
            const int q = qb + qi;
            if (q <= i) yb[(size_t)q * SS + (i - q)] = acc[bi][qi] + bvals[qi];
        }
    }
}

extern "C" void kernel_launch(void* const* d_in, const int* in_sizes, int n_in,
                              void* d_out, int out_size, void* d_ws, size_t ws_size,
                              hipStream_t stream) {
    const float* x    = (const float*)d_in[0];
    const float* W    = (const float*)d_in[1];
    const float* bias = (const float*)d_in[2];
    float* y          = (float*)d_out;

    const size_t D2_bytes = (size_t)64 * BB * SS * 16;           // 16.8 MB
    const size_t O_bytes  = (size_t)BB * SS * SS * sizeof(bf16); // 16.8 MB

    if (ws_size >= D2_bytes + O_bytes) {
        uint4* D2 = (uint4*)d_ws;
        bf16*  O  = (bf16*)((char*)d_ws + D2_bytes);
        gather_kernel<<<dim3(64, 32), dim3(256), 0, stream>>>(x, D2, y);
        mfma_gemm_pipe<<<dim3(512, 4), dim3(256), 0, stream>>>(D2, W, bias, O);
        shear_kernel<<<dim3(8, 8, 32), dim3(256), 0, stream>>>(O, x, y);
    } else {
        copy_x_kernel<<<dim3(8192), dim3(256), 0, stream>>>(x, y);
        diag_gemm_fallback<<<dim3(SS / TQ, SS), dim3(256), 0, stream>>>(x, W, bias, y);
    }
}

// Round 14
// 91.941 us; speedup vs baseline: 1.2491x; 1.0341x over previous
//
#include <hip/hip_runtime.h>
#include <hip/hip_bf16.h>
#include <stdint.h>

#define SS 512
#define BB 32
#define TQ 128

typedef __bf16 bf16;
typedef __attribute__((ext_vector_type(8))) __bf16 bf16x8;
typedef __attribute__((ext_vector_type(4))) float f32x4;

// ---------------------------------------------------------------------------
// Kernel A (fallback path only): y = x everywhere.
// ---------------------------------------------------------------------------
__global__ __launch_bounds__(256) void copy_x_kernel(const float* __restrict__ x,
                                                     float* __restrict__ y) {
    size_t idx = (size_t)blockIdx.x * 256 + threadIdx.x;
    reinterpret_cast<float4*>(y)[idx] = reinterpret_cast<const float4*>(x)[idx];
}

// ---------------------------------------------------------------------------
// Gather: D2[rb][b][i] (uint4 = 8 bf16, e-th elem = D[b, i, r=rb*8+e])
//   D[b,i,r] = x[b, r, i-r] if r <= i else 0
// ---------------------------------------------------------------------------
__global__ __launch_bounds__(256) void gather_kernel(const float* __restrict__ x,
                                                     uint4* __restrict__ D2) {
    const int rb = blockIdx.x;   // 0..63
    const int b  = blockIdx.y;   // 0..31
    __shared__ float xs[8][516];

    const int t = threadIdx.x;
    const float* xb = x + ((size_t)b * SS + rb * 8) * SS;
#pragma unroll
    for (int k = 0; k < 4; ++k) {
        int task = t + 256 * k;
        int c4 = task & 127;
        int e  = task >> 7;
        float4 v = *reinterpret_cast<const float4*>(xb + (size_t)e * SS + c4 * 4);
        *reinterpret_cast<float4*>(&xs[e][c4 * 4]) = v;
    }
    __syncthreads();

    const int r0 = rb * 8;
#pragma unroll
    for (int k = 0; k < 2; ++k) {
        int i = t + 256 * k;
        bf16x8 pack;
#pragma unroll
        for (int e = 0; e < 8; ++e) {
            int c  = i - (r0 + e);
            int cc = c < 0 ? 0 : c;
            float v = xs[e][cc];
            pack[e] = (c >= 0) ? (bf16)v : (bf16)0.0f;
        }
        D2[((size_t)rb * BB + b) * SS + i] = __builtin_bit_cast(uint4, pack);
    }
}

// ---------------------------------------------------------------------------
// MFMA GEMM (R7, best measured): depth-2 pipelined, raw barriers (lgkmcnt
// only -- global loads stay in flight across the barrier via counted vmcnt).
//   step k: MFMA(k) from LDS buf[k&1]; issue W/A(k+2); cvt+ds_write W(k+1).
// O output bf16, coalesced [b][i][q]; shear kernel finishes.
// i-mapping XCD-balanced (runs of 8, heavy-first).
// ---------------------------------------------------------------------------
__global__ __launch_bounds__(256) void mfma_gemm_pipe(const uint4* __restrict__ D2,
                                                      const float* __restrict__ W,
                                                      const float* __restrict__ bias,
                                                      bf16* __restrict__ O) {
    const int bid = (int)blockIdx.x;                 // 0..511
    const int xcd = bid & 7;
    const int m   = bid >> 3;                        // 0..63
    const int run = xcd + 8 * (m >> 3);
    const int i   = (SS - 1) - (run * 8 + (m & 7));  // heavy-first per XCD
    const int q0  = (int)blockIdx.y * TQ;
    if (q0 > i) return;

    const int qmax = ((i >> 4) + 1) * 16;
    const int qhi  = min(qmax - q0, TQ);
    const int nk   = (i >> 5) + 1;

    __shared__ bf16 Bs[2][TQ][40];                   // pitch 40: ~2-way max alias

    const int t    = (int)threadIdx.x;
    const int lane = t & 63;
    const int w    = t >> 6;
    const int l15  = lane & 15;
    const int lg   = lane >> 4;

    f32x4 acc00 = (f32x4)0.0f, acc01 = (f32x4)0.0f;
    f32x4 acc10 = (f32x4)0.0f, acc11 = (f32x4)0.0f;

    const float* Wi  = W + (size_t)i * SS * SS;
    const uint4* D2i = D2 + i;

    const int qq0 = t >> 2,         ch0 = t & 3;
    const int qq1 = (t + 256) >> 2, ch1 = (t + 256) & 3;
    const bool st0 = (t < qhi * 4);
    const bool st1 = (t + 256 < qhi * 4);

    const int qf0 = q0 + w * 16;
    const int qf1 = q0 + 64 + w * 16;
    const bool v0 = (qf0 <= i);                      // wave-uniform
    const bool v1 = (qf1 <= i);

    f32x4 eW0, eW1, eW2, eW3;                        // even-slot W staging regs
    f32x4 oW0, oW1, oW2, oW3;                        // odd-slot
    uint4 eA0, eA1, oA0, oA1;                        // A frags even/odd

#define ISSUE_W(kk, d0, d1, d2, d3)                                            \
    do {                                                                       \
        const int r0_ = (kk) * 32;                                             \
        if (st0) {                                                             \
            const float* wp_ = Wi + (size_t)(q0 + qq0) * SS + r0_ + ch0 * 8;   \
            d0 = *reinterpret_cast<const f32x4*>(wp_);                         \
            d1 = *reinterpret_cast<const f32x4*>(wp_ + 4);                     \
        }                                                                      \
        if (st1) {                                                             \
            const float* wp_ = Wi + (size_t)(q0 + qq1) * SS + r0_ + ch1 * 8;   \
            d2 = *reinterpret_cast<const f32x4*>(wp_);                         \
            d3 = *reinterpret_cast<const f32x4*>(wp_ + 4);                     \
        }                                                                      \
    } while (0)

#define ISSUE_A(kk, a0_, a1_)                                                  \
    do {                                                                       \
        const int rb_ = ((kk) * 32) >> 3;                                      \
        a0_ = D2i[(size_t)((rb_ + lg) * BB + l15) * SS];                       \
        a1_ = D2i[(size_t)((rb_ + lg) * BB + 16 + l15) * SS];                  \
    } while (0)

#define WRITE_B(buf_, d0, d1, d2, d3)                                          \
    do {                                                                       \
        if (st0) {                                                             \
            bf16x8 pk_;                                                        \
            pk_[0]=(bf16)d0.x; pk_[1]=(bf16)d0.y; pk_[2]=(bf16)d0.z; pk_[3]=(bf16)d0.w; \
            pk_[4]=(bf16)d1.x; pk_[5]=(bf16)d1.y; pk_[6]=(bf16)d1.z; pk_[7]=(bf16)d1.w; \
            *reinterpret_cast<uint4*>(&Bs[buf_][qq0][ch0 * 8]) = __builtin_bit_cast(uint4, pk_); \
        }                                                                      \
        if (st1) {                                                             \
            bf16x8 pk_;                                                        \
            pk_[0]=(bf16)d2.x; pk_[1]=(bf16)d2.y; pk_[2]=(bf16)d2.z; pk_[3]=(bf16)d2.w; \
            pk_[4]=(bf16)d3.x; pk_[5]=(bf16)d3.y; pk_[6]=(bf16)d3.z; pk_[7]=(bf16)d3.w; \
            *reinterpret_cast<uint4*>(&Bs[buf_][qq1][ch1 * 8]) = __builtin_bit_cast(uint4, pk_); \
        }                                                                      \
    } while (0)

// raw barrier: drain LDS only; global loads stay in flight (counted vmcnt).
#define BARRIER()                                                              \
    do {                                                                       \
        asm volatile("s_waitcnt lgkmcnt(0)" ::: "memory");                     \
        __builtin_amdgcn_s_barrier();                                          \
        __builtin_amdgcn_sched_barrier(0);                                     \
    } while (0)

#define MFMA_STEP(buf_, aa0_, aa1_)                                            \
    do {                                                                       \
        const bf16x8 a0v_ = __builtin_bit_cast(bf16x8, aa0_);                  \
        const bf16x8 a1v_ = __builtin_bit_cast(bf16x8, aa1_);                  \
        if (v0) {                                                              \
            uint4 bv_ = *reinterpret_cast<const uint4*>(&Bs[buf_][w * 16 + l15][lg * 8]); \
            bf16x8 bb_ = __builtin_bit_cast(bf16x8, bv_);                      \
            acc00 = __builtin_amdgcn_mfma_f32_16x16x32_bf16(a0v_, bb_, acc00, 0, 0, 0); \
            acc01 = __builtin_amdgcn_mfma_f32_16x16x32_bf16(a1v_, bb_, acc01, 0, 0, 0); \
        }                                                                      \
        if (v1) {                                                              \
            uint4 bv_ = *reinterpret_cast<const uint4*>(&Bs[buf_][64 + w * 16 + l15][lg * 8]); \
            bf16x8 bb_ = __builtin_bit_cast(bf16x8, bv_);                      \
            acc10 = __builtin_amdgcn_mfma_f32_16x16x32_bf16(a0v_, bb_, acc10, 0, 0, 0); \
            acc11 = __builtin_amdgcn_mfma_f32_16x16x32_bf16(a1v_, bb_, acc11, 0, 0, 0); \
        }                                                                      \
    } while (0)

    // prologue: W(0),A(0) -> even set; W(1),A(1) -> odd set; stage buf0.
    ISSUE_W(0, eW0, eW1, eW2, eW3);
    ISSUE_A(0, eA0, eA1);
    if (nk > 1) { ISSUE_W(1, oW0, oW1, oW2, oW3); ISSUE_A(1, oA0, oA1); }
    WRITE_B(0, eW0, eW1, eW2, eW3);
    BARRIER();

    for (int kk = 0; kk < nk; kk += 2) {
        // ---- even step kk: B from buf0, A = even set ----
        MFMA_STEP(0, eA0, eA1);
        if (kk + 2 < nk) {
            ISSUE_W(kk + 2, eW0, eW1, eW2, eW3);
            ISSUE_A(kk + 2, eA0, eA1);
        }
        if (kk + 1 < nk) {
            WRITE_B(1, oW0, oW1, oW2, oW3);      // W(k+1): issued 1 step ago
            BARRIER();
            // ---- odd step kk+1: B from buf1, A = odd set ----
            MFMA_STEP(1, oA0, oA1);
            if (kk + 3 < nk) {
                ISSUE_W(kk + 3, oW0, oW1, oW2, oW3);
                ISSUE_A(kk + 3, oA0, oA1);
            }
            if (kk + 2 < nk) {
                WRITE_B(0, eW0, eW1, eW2, eW3);
                BARRIER();
            }
        }
    }

#undef ISSUE_W
#undef ISSUE_A
#undef WRITE_B
#undef BARRIER
#undef MFMA_STEP

    // epilogue: C/D layout col(q)=lane&15, row(b)=(lane>>4)*4+reg; O is bf16.
    if (v0) {
        const int q = qf0 + l15;
        const float bv = bias[(size_t)i * SS + q];
#pragma unroll
        for (int v = 0; v < 4; ++v) {
            O[((size_t)(lg * 4 + v) * SS + i) * SS + q]      = (bf16)(acc00[v] + bv);
            O[((size_t)(16 + lg * 4 + v) * SS + i) * SS + q] = (bf16)(acc01[v] + bv);
        }
    }
    if (v1) {
        const int q = qf1 + l15;
        const float bv = bias[(size_t)i * SS + q];
#pragma unroll
        for (int v = 0; v < 4; ++v) {
            O[((size_t)(lg * 4 + v) * SS + i) * SS + q]      = (bf16)(acc10[v] + bv);
            O[((size_t)(16 + lg * 4 + v) * SS + i) * SS + q] = (bf16)(acc11[v] + bv);
        }
    }
}

// ---------------------------------------------------------------------------
// Shear: y[b][q][c] = (q+c < S) ? O[b][q+c][q] : x[b][q][c].  O is bf16.
// ---------------------------------------------------------------------------
__global__ __launch_bounds__(256) void shear_kernel(const bf16* __restrict__ O,
                                                    const float* __restrict__ x,
                                                    float* __restrict__ y) {
    const int c0 = (int)blockIdx.x * 64;
    const int q0 = (int)blockIdx.y * 64;
    const int b  = (int)blockIdx.z;
    const int t  = (int)threadIdx.x;
    const float* xb = x + (size_t)b * SS * SS;
    float* yb       = y + (size_t)b * SS * SS;
    const int i0 = q0 + c0;

    if (i0 >= SS) {   // pure passthrough tile
#pragma unroll
        for (int k = 0; k < 4; ++k) {
            int task = t + 256 * k;
            int qq = task >> 4, c4 = (task & 15) * 4;
            size_t off = (size_t)(q0 + qq) * SS + c0 + c4;
            *reinterpret_cast<float4*>(yb + off) =
                *reinterpret_cast<const float4*>(xb + off);
        }
        return;
    }

    __shared__ float Os[127 * 67];
    const int nrows = min(127, SS - i0);
    const bf16* Ob = O + (size_t)b * SS * SS;

    for (int task = t; task < nrows * 8; task += 256) {
        int rr = task >> 3, c8 = (task & 7) * 8;
        bf16x8 v = *reinterpret_cast<const bf16x8*>(Ob + (size_t)(i0 + rr) * SS + q0 + c8);
        float* d = &Os[rr * 67 + c8];
#pragma unroll
        for (int e = 0; e < 8; ++e) d[e] = (float)v[e];
    }
    __syncthreads();

#pragma unroll
    for (int k = 0; k < 4; ++k) {
        int task = t + 256 * k;
        int qq = task >> 4, c4 = (task & 15) * 4;
        int q = q0 + qq, c = c0 + c4;
        float4 o;
        if (i0 + qq + c4 + 3 < SS) {
            o.x = Os[(qq + c4 + 0) * 67 + qq];
            o.y = Os[(qq + c4 + 1) * 67 + qq];
            o.z = Os[(qq + c4 + 2) * 67 + qq];
            o.w = Os[(qq + c4 + 3) * 67 + qq];
        } else {
            float tmp[4];
#pragma unroll
            for (int kk = 0; kk < 4; ++kk) {
                tmp[kk] = (q + c + kk < SS) ? Os[(qq + c4 + kk) * 67 + qq]
                                            : xb[(size_t)q * SS + c + kk];
            }
            o = make_float4(tmp[0], tmp[1], tmp[2], tmp[3]);
        }
        *reinterpret_cast<float4*>(yb + (size_t)q * SS + c) = o;
    }
}

// ---------------------------------------------------------------------------
// f32 fallback (round-1), only if ws_size is tiny.
// ---------------------------------------------------------------------------
#define FTK 32
#define FWROW (TQ + 4)
__global__ __launch_bounds__(256) void diag_gemm_fallback(const float* __restrict__ x,
                                                          const float* __restrict__ W,
                                                          const float* __restrict__ bias,
                                                          float* __restrict__ y) {
    const int i  = (SS - 1) - (int)blockIdx.y;
    const int q0 = (int)blockIdx.x * TQ;
    if (q0 > i) return;
    __shared__ float Ds[FTK][BB];
    __shared__ float Ws[FTK][FWROW];
    const int tid = (int)threadIdx.x;
    const int qg  = tid & 31;
    const int bg  = tid >> 5;
    float acc[4][4];
#pragma unroll
    for (int a = 0; a < 4; ++a)
#pragma unroll
        for (int c = 0; c < 4; ++c) acc[a][c] = 0.0f;
    const float* Wi = W + (size_t)i * SS * SS;
    for (int r0 = 0; r0 <= i; r0 += FTK) {
        __syncthreads();
        {
            const int rr = tid >> 3;
            const int b4 = (tid & 7) * 4;
            const int r  = r0 + rr;
            float4 dv = make_float4(0.f, 0.f, 0.f, 0.f);
            if (r <= i) {
                const int col = i - r;
                dv.x = x[((size_t)(b4 + 0) * SS + r) * SS + col];
                dv.y = x[((size_t)(b4 + 1) * SS + r) * SS + col];
                dv.z = x[((size_t)(b4 + 2) * SS + r) * SS + col];
                dv.w = x[((size_t)(b4 + 3) * SS + r) * SS + col];
            }
            *reinterpret_cast<float4*>(&Ds[rr][b4]) = dv;
        }
#pragma unroll
        for (int l = 0; l < 4; ++l) {
            const int idx = tid + 256 * l;
            const int qL  = idx >> 3;
            const int rc  = idx & 7;
            const int r   = r0 + rc * 4;
            const float* wp = Wi + (size_t)(q0 + qL) * SS;
            float4 wv;
            if (r + 3 < SS) {
                wv = *reinterpret_cast<const float4*>(wp + r);
            } else {
                wv.x = wp[min(r + 0, SS - 1)];
                wv.y = wp[min(r + 1, SS - 1)];
                wv.z = wp[min(r + 2, SS - 1)];
                wv.w = wp[min(r + 3, SS - 1)];
            }
            Ws[rc * 4 + 0][qL] = wv.x;
            Ws[rc * 4 + 1][qL] = wv.y;
            Ws[rc * 4 + 2][qL] = wv.z;
            Ws[rc * 4 + 3][qL] = wv.w;
        }
        __syncthreads();
#pragma unroll
        for (int rr = 0; rr < FTK; ++rr) {
            const float4 d4 = *reinterpret_cast<const float4*>(&Ds[rr][bg * 4]);
            const float4 w4 = *reinterpret_cast<const float4*>(&Ws[rr][qg * 4]);
            acc[0][0] = fmaf(d4.x, w4.x, acc[0][0]); acc[0][1] = fmaf(d4.x, w4.y, acc[0][1]);
            acc[0][2] = fmaf(d4.x, w4.z, acc[0][2]); acc[0][3] = fmaf(d4.x, w4.w, acc[0][3]);
            acc[1][0] = fmaf(d4.y, w4.x, acc[1][0]); acc[1][1] = fmaf(d4.y, w4.y, acc[1][1]);
            acc[1][2] = fmaf(d4.y, w4.z, acc[1][2]); acc[1][3] = fmaf(d4.y, w4.w, acc[1][3]);
            acc[2][0] = fmaf(d4.z, w4.x, acc[2][0]); acc[2][1] = fmaf(d4.z, w4.y, acc[2][1]);
            acc[2][2] = fmaf(d4.z, w4.z, acc[2][2]); acc[2][3] = fmaf(d4.z, w4.w, acc[2][3]);
            acc[3][0] = fmaf(d4.w, w4.x, acc[3][0]); acc[3][1] = fmaf(d4.w, w4.y, acc[3][1]);
            acc[3][2] = fmaf(d4.w, w4.z, acc[3][2]); acc[3][3] = fmaf(d4.w, w4.w, acc[3][3]);
        }
    }
    const int qb = q0 + qg * 4;
    const float4 bv = *reinterpret_cast<const float4*>(bias + (size_t)i * SS + qb);
    const float bvals[4] = {bv.x, bv.y, bv.z, bv.w};
#pragma unroll
    for (int bi = 0; bi < 4; ++bi) {
        const int b = bg * 4 + bi;
        float* yb = y + (size_t)b * SS * SS;
#pragma unroll
        for (int qi = 0; qi < 4; ++qi) {
            const int q = qb + qi;
            if (q <= i) yb[(size_t)q * SS + (i - q)] = acc[bi][qi] + bvals[qi];
        }
    }
}

extern "C" void kernel_launch(void* const* d_in, const int* in_sizes, int n_in,
                              void* d_out, int out_size, void* d_ws, size_t ws_size,
                              hipStream_t stream) {
    const float* x    = (const float*)d_in[0];
    const float* W    = (const float*)d_in[1];
    const float* bias = (const float*)d_in[2];
    float* y          = (float*)d_out;

    const size_t D2_bytes = (size_t)64 * BB * SS * 16;           // 16.8 MB
    const size_t O_bytes  = (size_t)BB * SS * SS * sizeof(bf16); // 16.8 MB

    if (ws_size >= D2_bytes + O_bytes) {
        uint4* D2 = (uint4*)d_ws;
        bf16*  O  = (bf16*)((char*)d_ws + D2_bytes);
        gather_kernel<<<dim3(64, 32), dim3(256), 0, stream>>>(x, D2);
        mfma_gemm_pipe<<<dim3(512, 4), dim3(256), 0, stream>>>(D2, W, bias, O);
        shear_kernel<<<dim3(8, 8, 32), dim3(256), 0, stream>>>(O, x, y);
    } else {
        copy_x_kernel<<<dim3(8192), dim3(256), 0, stream>>>(x, y);
        diag_gemm_fallback<<<dim3(SS / TQ, SS), dim3(256), 0, stream>>>(x, W, bias, y);
    }
}